// Round 12
// baseline (537.961 us; speedup 1.0000x reference)
//
#include <hip/hip_runtime.h>
#include <math.h>

typedef unsigned int u32;
typedef unsigned long long u64;
typedef unsigned short u16;

typedef float f32x16 __attribute__((ext_vector_type(16)));
typedef short bf16x8 __attribute__((ext_vector_type(8)));

#define A_TOTAL 49152
#define NKEEP 2000
#define NTOPK 300
#define SORTN 4096

// ws layout (bytes)
#define OFF_PACC   0u            // [2][512][4096] f32 = 16,777,216 (conv1 kh-partials)
#define OFF_LOG    16777216u     // [60][4096] f32 logits (bias included) = 983,040
#define OFF_SCORES 17760256u     // 49152 f32
#define OFF_HIST   17956864u     // 65536 u32
#define OFF_KEYS   18219008u     // 4096 u64
#define OFF_CAND5  18251776u     // 2048*5 f32
#define OFF_MASK   18292736u     // 2048*32 u64
#define OFF_MISC   18817024u     // [0]=counter,[1]=B1 ; +64B: suppws u64[32]
#define OFF_PREW   18821120u     // [2kh][8yb][32c][3s][1152 units x 16B] = 28,311,552
#define WS_NEED    47132672ull

__global__ __launch_bounds__(256) void k_init(u32* __restrict__ hist, u64* __restrict__ keys,
                                              u32* __restrict__ misc, float* __restrict__ out) {
    int t = blockIdx.x * 256 + threadIdx.x;
    if (t < 65536) hist[t] = 0u;
    if (t < SORTN) keys[t] = 0ull;
    if (t < NTOPK * 5) out[t] = 0.f;
    if (t == 0) misc[0] = 0u;
}

// ---------- bf16 split helpers (all RNE — R7/R9/R11-validated numerics, LOCKED) ----------
__device__ __forceinline__ u16 f2bf(float v) {
    u32 u = __float_as_uint(v);
    return (u16)((u + 0x7FFFu + ((u >> 16) & 1u)) >> 16);
}
__device__ __forceinline__ float bf2f(u16 h) { return __uint_as_float(((u32)h) << 16); }
__device__ __forceinline__ void split3(float v, u16& h, u16& m, u16& l) {
    h = f2bf(v);
    float r1 = v - bf2f(h);
    m = f2bf(r1);
    float r2 = r1 - bf2f(m);
    l = f2bf(r2);
}
__device__ __forceinline__ bf16x8 ldsfrag(const u16* p) {
    const u64* q = (const u64*)p;
    union { u64 w[2]; bf16x8 v; } x;
    x.w[0] = q[0];
    x.w[1] = q[1];
    return x.v;
}
__device__ __forceinline__ void gll16(const void* g, void* l) {
    __builtin_amdgcn_global_load_lds((const __attribute__((address_space(1))) void*)g,
                                     (__attribute__((address_space(3))) void*)l, 16, 0, 0);
}
__device__ __forceinline__ void gll4(const void* g, void* l) {
    __builtin_amdgcn_global_load_lds((const __attribute__((address_space(1))) void*)g,
                                     (__attribute__((address_space(3))) void*)l, 4, 0, 0);
}

// Pre-split w1 -> preW bf16 triples in conv1m's exact LDS order, COALESCED version:
// one block per (kh,yb,c) chunk; reads w1 in contiguous 144-float runs per co (576B),
// LDS-transposes to target unit order, writes preW coalesced.
// preW[(((kh*8+yb)*32+c)*3+s)*1152 + (tap*2+g)*64 + co] (uint4); unit = 8 bf16 (ci octet).
__global__ __launch_bounds__(256) void k_splitw(const float* __restrict__ w1, uint4* __restrict__ preW) {
    __shared__ __align__(16) u16 sW[3 * 9216];   // [s][((tap*2+g)*64+co)*8 + ci&7]
    const int tid = threadIdx.x;
    const int c = blockIdx.x;
    const int yb = blockIdx.y;
    const int kh = blockIdx.z;
    const float* base = w1 + (size_t)(yb * 64) * 9216 + (size_t)(kh * 512 + c * 16) * 9;
#pragma unroll
    for (int j = 0; j < 36; j++) {
        int e = tid + j * 256;           // 0..9215 = 64co x 144 (ci*9+tap)
        int co = e / 144, r = e - co * 144;
        int ci = r / 9, tap = r - ci * 9;
        float v = base[(size_t)co * 9216 + r];
        u16 h, m, l;
        split3(v, h, m, l);
        int li = ((tap * 2 + (ci >> 3)) * 64 + co) * 8 + (ci & 7);
        sW[li] = h; sW[9216 + li] = m; sW[18432 + li] = l;
    }
    __syncthreads();
    const uint4* sw4 = (const uint4*)sW;         // 3456 units
    uint4* dst = preW + (size_t)(((kh * 8 + yb) * 32 + c) * 3) * 1152;
#pragma unroll
    for (int j = 0; j < 14; j++) {
        int e = tid + j * 256;
        if (e < 3456) dst[e] = sw4[e];
    }
}

// conv1 via MFMA bf16x3 splits, 6 terms — R11-validated verbatim.
__global__ __launch_bounds__(512) void k_conv1m(const float* __restrict__ fx, const uint4* __restrict__ preW,
                                                float* __restrict__ pacc) {
    __shared__ __align__(16) u16 sA[3 * 9216];
    __shared__ __align__(16) u16 sB[3 * 3600];
    u32* const sB32 = (u32*)sB;
    const int tid = threadIdx.x;
    const int lane = tid & 63;
    const int wid = tid >> 6;
    const int cgw = wid >> 2;
    const int pgw = wid & 3;
    const int n = lane & 31;
    const int g = lane >> 5;
    const int bid = blockIdx.x;
    const int yb = bid & 7;
    const int rest = bid >> 3;
    const int bpx = rest & 31;
    const int kh = rest >> 5;
    const int y0 = (bpx >> 2) * 8, x0 = (bpx & 3) * 16;
    const int ci_base = kh * 512;

    int fgp[3], flp[3];
    bool wrp[3], ldp[3];
#pragma unroll
    for (int j = 0; j < 3; j++) {
        int p = tid + j * 512;
        bool wr = p < 1440;
        int a = p / 180, rem = p - a * 180;
        int hy = rem / 18, hx = rem - hy * 18;
        int gy = y0 + hy - 1, gx = x0 + hx - 1;
        bool ok = wr && gy >= 0 && gy < 64 && gx >= 0 && gx < 64;
        wrp[j] = wr;
        ldp[j] = ok;
        fgp[j] = ok ? ((2 * a) * 4096 + gy * 64 + gx) : 0;
        flp[j] = wr ? (rem * 10 + a) : 0;
    }

    f32x16 acc;
    double accD[16];
#pragma unroll
    for (int i = 0; i < 16; i++) { acc[i] = 0.f; accD[i] = 0.0; }

    float pA0[3], pA1[3], pB0[3], pB1[3];
    {
        const float* f0 = fx + (size_t)ci_base * 4096;
        const float* f1 = fx + (size_t)(ci_base + 16) * 4096;
#pragma unroll
        for (int j = 0; j < 3; j++) {
            pA0[j] = ldp[j] ? f0[fgp[j]] : 0.f;
            pA1[j] = ldp[j] ? f0[fgp[j] + 4096] : 0.f;
            pB0[j] = ldp[j] ? f1[fgp[j]] : 0.f;
            pB1[j] = ldp[j] ? f1[fgp[j] + 4096] : 0.f;
        }
    }
    const char* wbase = (const char*)preW + (size_t)((kh * 8 + yb) * 32) * 3 * 18432;
    char* const sAc = (char*)sA;

#pragma unroll 1
    for (int c = 0; c < 32; c++) {
        __syncthreads();
        const char* wsrc = wbase + (size_t)c * 3 * 18432;
#pragma unroll
        for (int s = 0; s < 3; s++) {
            gll16(wsrc + s * 18432 + tid * 16,         sAc + s * 18432 + wid * 1024);
            gll16(wsrc + s * 18432 + 8192 + tid * 16,  sAc + s * 18432 + 8192 + wid * 1024);
            gll4 (wsrc + s * 18432 + 16384 + tid * 4,  sAc + s * 18432 + 16384 + wid * 256);
        }
#pragma unroll
        for (int j = 0; j < 3; j++) {
            if (wrp[j]) {
                u16 h0, m0, l0, h1, m1, l1;
                split3(pA0[j], h0, m0, l0);
                split3(pA1[j], h1, m1, l1);
                sB32[flp[j]] = (u32)h0 | ((u32)h1 << 16);
                sB32[1800 + flp[j]] = (u32)m0 | ((u32)m1 << 16);
                sB32[3600 + flp[j]] = (u32)l0 | ((u32)l1 << 16);
            }
        }
        __syncthreads();
#pragma unroll
        for (int j = 0; j < 3; j++) { pA0[j] = pB0[j]; pA1[j] = pB1[j]; }
        if (c < 30) {
            const float* fp = fx + (size_t)(ci_base + (c + 2) * 16) * 4096;
#pragma unroll
            for (int j = 0; j < 3; j++) {
                pB0[j] = ldp[j] ? fp[fgp[j]] : 0.f;
                pB1[j] = ldp[j] ? fp[fgp[j] + 4096] : 0.f;
            }
        }

#pragma unroll 1
        for (int dy = 0; dy < 3; dy++) {
#pragma unroll
            for (int dx = 0; dx < 3; dx++) {
                const int tap = dy * 3 + dx;
                const int aoff = ((tap * 2 + g) * 64 + cgw * 32 + n) * 8;
                bf16x8 ah = ldsfrag(&sA[aoff]);
                bf16x8 am = ldsfrag(&sA[9216 + aoff]);
                bf16x8 al = ldsfrag(&sA[18432 + aoff]);
                const int loc = (pgw * 2 + (n >> 4) + dy) * 18 + (n & 15) + dx;
                const int boff = loc * 20 + g * 8;
                bf16x8 bh = ldsfrag(&sB[boff]);
                bf16x8 bm = ldsfrag(&sB[3600 + boff]);
                bf16x8 bl = ldsfrag(&sB[7200 + boff]);
                acc = __builtin_amdgcn_mfma_f32_32x32x16_bf16(ah, bh, acc, 0, 0, 0);
                acc = __builtin_amdgcn_mfma_f32_32x32x16_bf16(ah, bm, acc, 0, 0, 0);
                acc = __builtin_amdgcn_mfma_f32_32x32x16_bf16(am, bh, acc, 0, 0, 0);
                acc = __builtin_amdgcn_mfma_f32_32x32x16_bf16(ah, bl, acc, 0, 0, 0);
                acc = __builtin_amdgcn_mfma_f32_32x32x16_bf16(am, bm, acc, 0, 0, 0);
                acc = __builtin_amdgcn_mfma_f32_32x32x16_bf16(al, bh, acc, 0, 0, 0);
            }
#pragma unroll
            for (int i = 0; i < 16; i++) { accD[i] += (double)acc[i]; acc[i] = 0.f; }
        }
    }

    {
        int p = pgw * 32 + n;
        int py = p >> 4, pxx = p & 15;
        int gp = (y0 + py) * 64 + x0 + pxx;
        const int row_hi = 4 * g;
#pragma unroll
        for (int rg = 0; rg < 16; rg++) {
            int co = yb * 64 + cgw * 32 + (rg & 3) + 8 * (rg >> 2) + row_hi;
            pacc[(size_t)kh * 2097152 + (size_t)co * 4096 + gp] = (float)accD[rg];
        }
    }
}

// Fallback (ws too small for preW): R9/R11 runtime-split kernel verbatim.
__global__ __launch_bounds__(512) void k_conv1m_fb(const float* __restrict__ fx, const float* __restrict__ w1,
                                                   float* __restrict__ pacc) {
    __shared__ u16 sA[3 * 9472];
    __shared__ u16 sB[3 * 3600];
    u32* const sA32 = (u32*)sA;
    const int tid = threadIdx.x;
    const int lane = tid & 63;
    const int wid = tid >> 6;
    const int cgw = wid >> 2;
    const int pgw = wid & 3;
    const int n = lane & 31;
    const int g = lane >> 5;
    const int bid = blockIdx.x;
    const int yb = bid & 7;
    const int rest = bid >> 3;
    const int bpx = rest & 31;
    const int kh = rest >> 5;
    const int y0 = (bpx >> 2) * 8, x0 = (bpx & 3) * 16;
    const int co0 = yb * 64;
    const int ci_base = kh * 512;

    int wgp[9], wlp[9];
#pragma unroll
    for (int j = 0; j < 9; j++) {
        int p = tid + j * 512;
        int co = p / 72, q = p - co * 72;
        int a = q & 7, b = q >> 3;
        wgp[j] = co * 9216 + (2 * a) * 9 + b;
        wlp[j] = co * 74 + b * 8 + a;
    }
    int fg0[6], fl[6];
#pragma unroll
    for (int j = 0; j < 6; j++) {
        int idx = tid + j * 512;
        bool wr = idx < 2880;
        int ci = idx / 180, rem = idx - ci * 180;
        int hy = rem / 18, hx = rem - hy * 18;
        int gy = y0 + hy - 1, gx = x0 + hx - 1;
        bool ok = wr && gy >= 0 && gy < 64 && gx >= 0 && gx < 64;
        fg0[j] = ok ? (ci * 4096 + gy * 64 + gx) : -1;
        fl[j] = wr ? (rem * 20 + ci) : -1;
    }

    f32x16 acc;
    double accD[16];
#pragma unroll
    for (int i = 0; i < 16; i++) { acc[i] = 0.f; accD[i] = 0.0; }

    float pw[18], pfA[6], pfB[6];
    {
        const float* wp = w1 + (size_t)co0 * 9216 + (size_t)ci_base * 9;
#pragma unroll
        for (int j = 0; j < 9; j++) { pw[2 * j] = wp[wgp[j]]; pw[2 * j + 1] = wp[wgp[j] + 9]; }
        const float* f0 = fx + (size_t)ci_base * 4096;
        const float* f1 = fx + (size_t)(ci_base + 16) * 4096;
#pragma unroll
        for (int j = 0; j < 6; j++) {
            pfA[j] = (fg0[j] >= 0) ? f0[fg0[j]] : 0.f;
            pfB[j] = (fg0[j] >= 0) ? f1[fg0[j]] : 0.f;
        }
    }

#pragma unroll 1
    for (int c = 0; c < 32; c++) {
        __syncthreads();
#pragma unroll
        for (int j = 0; j < 9; j++) {
            u16 h0, m0, l0, h1, m1, l1;
            split3(pw[2 * j], h0, m0, l0);
            split3(pw[2 * j + 1], h1, m1, l1);
            sA32[wlp[j]] = (u32)h0 | ((u32)h1 << 16);
            sA32[4736 + wlp[j]] = (u32)m0 | ((u32)m1 << 16);
            sA32[9472 + wlp[j]] = (u32)l0 | ((u32)l1 << 16);
        }
#pragma unroll
        for (int j = 0; j < 6; j++) {
            if (fl[j] >= 0) {
                u16 h, m, l;
                split3(pfA[j], h, m, l);
                sB[fl[j]] = h; sB[3600 + fl[j]] = m; sB[7200 + fl[j]] = l;
            }
        }
        __syncthreads();
        if (c < 31) {
            const float* wp = w1 + (size_t)co0 * 9216 + (size_t)(ci_base + (c + 1) * 16) * 9;
#pragma unroll
            for (int j = 0; j < 9; j++) { pw[2 * j] = wp[wgp[j]]; pw[2 * j + 1] = wp[wgp[j] + 9]; }
        }
#pragma unroll
        for (int j = 0; j < 6; j++) pfA[j] = pfB[j];
        if (c < 30) {
            const float* fp = fx + (size_t)(ci_base + (c + 2) * 16) * 4096;
#pragma unroll
            for (int j = 0; j < 6; j++) pfB[j] = (fg0[j] >= 0) ? fp[fg0[j]] : 0.f;
        }

#pragma unroll 1
        for (int dy = 0; dy < 3; dy++) {
#pragma unroll
            for (int dx = 0; dx < 3; dx++) {
                const int tap = dy * 3 + dx;
                const int aoff = (cgw * 32 + n) * 148 + tap * 16 + g * 8;
                bf16x8 ah = ldsfrag(&sA[aoff]);
                bf16x8 am = ldsfrag(&sA[9472 + aoff]);
                bf16x8 al = ldsfrag(&sA[18944 + aoff]);
                const int loc = (pgw * 2 + (n >> 4) + dy) * 18 + (n & 15) + dx;
                const int boff = loc * 20 + g * 8;
                bf16x8 bh = ldsfrag(&sB[boff]);
                bf16x8 bm = ldsfrag(&sB[3600 + boff]);
                bf16x8 bl = ldsfrag(&sB[7200 + boff]);
                acc = __builtin_amdgcn_mfma_f32_32x32x16_bf16(ah, bh, acc, 0, 0, 0);
                acc = __builtin_amdgcn_mfma_f32_32x32x16_bf16(ah, bm, acc, 0, 0, 0);
                acc = __builtin_amdgcn_mfma_f32_32x32x16_bf16(am, bh, acc, 0, 0, 0);
                acc = __builtin_amdgcn_mfma_f32_32x32x16_bf16(ah, bl, acc, 0, 0, 0);
                acc = __builtin_amdgcn_mfma_f32_32x32x16_bf16(am, bm, acc, 0, 0, 0);
                acc = __builtin_amdgcn_mfma_f32_32x32x16_bf16(al, bh, acc, 0, 0, 0);
            }
#pragma unroll
            for (int i = 0; i < 16; i++) { accD[i] += (double)acc[i]; acc[i] = 0.f; }
        }
    }

    {
        int p = pgw * 32 + n;
        int py = p >> 4, pxx = p & 15;
        int gp = (y0 + py) * 64 + x0 + pxx;
        const int row_hi = 4 * g;
#pragma unroll
        for (int rg = 0; rg < 16; rg++) {
            int co = co0 + cgw * 32 + (rg & 3) + 8 * (rg >> 2) + row_hi;
            pacc[(size_t)kh * 2097152 + (size_t)co * 4096 + gp] = (float)accD[rg];
        }
    }
}

// Fused: x = relu(f32(p0+p1+b1)) staged in LDS (bitwise = old k_comb), full-K 1x1 convs
// (f64 accumulate over all 512 ci, ascending order), writes FINAL f32 logits (bias added,
// same rounding point as validated k_boxes). grid 64 px-tiles, block 256 = 64px x 4og x 15o.
__global__ __launch_bounds__(256) void k_conv23f(const float* __restrict__ pacc,
                                                 const float* __restrict__ b1,
                                                 const float* __restrict__ w2, const float* __restrict__ b2,
                                                 const float* __restrict__ w3, const float* __restrict__ b3,
                                                 float* __restrict__ logit) {
    __shared__ float xs[32 * 64];     // [ci][px]
    __shared__ float wsh[60 * 32];    // [o][ci]
    const int tid = threadIdx.x;
    const int px0 = blockIdx.x * 64;
    const int px = tid & 63;
    const int og = tid >> 6;          // 0..3 -> o = og*15 + j

    double acc[15];
#pragma unroll
    for (int j = 0; j < 15; j++) acc[j] = 0.0;

#pragma unroll 1
    for (int ch = 0; ch < 16; ch++) {
        __syncthreads();
        // stage weights 60x32 for this ci-chunk
#pragma unroll
        for (int k = 0; k < 8; k++) {
            int e = tid + k * 256;
            if (e < 1920) {
                int o = e >> 5, ci = e & 31;
                wsh[o * 32 + ci] = (o < 12) ? w2[o * 512 + ch * 32 + ci]
                                            : w3[(size_t)(o - 12) * 512 + ch * 32 + ci];
            }
        }
        // stage x = relu(f32(p0 + p1 + b1)) — identical bits to old k_comb
#pragma unroll
        for (int k = 0; k < 8; k++) {
            int e = tid + k * 256;
            int ci = e >> 6, p = e & 63;
            size_t gi = (size_t)(ch * 32 + ci) * 4096 + px0 + p;
            double v = (double)pacc[gi] + (double)pacc[2097152 + gi] + (double)b1[ch * 32 + ci];
            xs[ci * 64 + p] = fmaxf((float)v, 0.f);
        }
        __syncthreads();
#pragma unroll 1
        for (int ci = 0; ci < 32; ci++) {
            double xd = (double)xs[ci * 64 + px];
            const float* wrow = &wsh[ci];
#pragma unroll
            for (int j = 0; j < 15; j++)
                acc[j] = fma(xd, (double)wrow[(og * 15 + j) * 32], acc[j]);
        }
    }
#pragma unroll
    for (int j = 0; j < 15; j++) {
        int o = og * 15 + j;
        float bias = (o < 12) ? b2[o] : b3[o - 12];
        logit[(size_t)o * 4096 + px0 + px] = (float)(acc[j] + (double)bias);
    }
}

// scores: f64 sigmoid of objectness logits + 16-bit-prefix histogram
__global__ __launch_bounds__(256) void k_scores(const float* __restrict__ logit,
                                                float* __restrict__ scores, u32* __restrict__ hist) {
    int idx = blockIdx.x * 256 + threadIdx.x;
    if (idx >= A_TOTAL) return;
    int px = idx / 12, a = idx - px * 12;
    float o = logit[(size_t)a * 4096 + px];
    float s = (float)(1.0 / (1.0 + exp(-(double)o)));
    scores[idx] = s;
    atomicAdd(&hist[__float_as_uint(s) >> 16], 1u);
}

// find boundary bin B1 so that count(bins >= B1) >= 2000, count(bins > B1) < 2000
__global__ __launch_bounds__(256) void k_scanhist(const u32* __restrict__ hist, u32* __restrict__ misc) {
    __shared__ u32 csum[256];
    __shared__ u32 cb[256];
    __shared__ int s_cidx;
    __shared__ u32 s_cacc;
    int t = threadIdx.x;
    u32 sum = 0;
    const uint4* h4 = (const uint4*)(hist + t * 256);
    for (int j = 0; j < 64; j++) { uint4 v = h4[j]; sum += v.x + v.y + v.z + v.w; }
    csum[t] = sum;
    __syncthreads();
    if (t == 0) {
        u32 acc = 0;
        int c = 255;
        for (; c > 0; c--) {
            if (acc + csum[c] >= NKEEP) break;
            acc += csum[c];
        }
        s_cidx = c;
        s_cacc = acc;
    }
    __syncthreads();
    cb[t] = hist[s_cidx * 256 + t];
    __syncthreads();
    if (t == 0) {
        u32 acc = s_cacc;
        int b = 255;
        for (; b > 0; b--) {
            acc += cb[b];
            if (acc >= NKEEP) break;
        }
        misc[1] = (u32)(s_cidx * 256 + b);
    }
}

__global__ __launch_bounds__(256) void k_compact(const float* __restrict__ scores, u32* __restrict__ misc,
                                                 u64* __restrict__ keys) {
    int idx = blockIdx.x * 256 + threadIdx.x;
    if (idx >= A_TOTAL) return;
    u32 bits = __float_as_uint(scores[idx]);
    if ((bits >> 16) >= misc[1]) {
        u32 slot = atomicAdd(&misc[0], 1u);
        if (slot < SORTN) keys[slot] = ((u64)bits << 32) | (u64)(~(u32)idx);
    }
}

// bitonic sort 4096 keys DESC (score desc, index asc); epilogue decodes top-2000 boxes
// from logits (same f64 formulas/rounding as validated k_boxes) + init suppression words.
__global__ __launch_bounds__(1024) void k_sort(const u64* __restrict__ keys, const float* __restrict__ logit,
                                               const int* __restrict__ imh, const int* __restrict__ imw,
                                               float* __restrict__ cand5, u64* __restrict__ suppws) {
    __shared__ u64 lk[SORTN];
    int t = threadIdx.x;
#pragma unroll
    for (int r = 0; r < 4; r++) lk[r * 1024 + t] = keys[r * 1024 + t];
    for (int kk = 2; kk <= SORTN; kk <<= 1) {
        for (int jj = kk >> 1; jj > 0; jj >>= 1) {
            __syncthreads();
#pragma unroll
            for (int rep = 0; rep < 4; rep++) {
                int i = rep * 1024 + t;
                int ixj = i ^ jj;
                if (ixj > i) {
                    u64 a = lk[i], b = lk[ixj];
                    bool sw = ((i & kk) == 0) ? (a < b) : (a > b);
                    if (sw) { lk[i] = b; lk[ixj] = a; }
                }
            }
        }
    }
    __syncthreads();
    float W = (float)imw[0], H = (float)imh[0];
#pragma unroll
    for (int rep = 0; rep < 2; rep++) {
        int i = rep * 1024 + t;
        bool suppb = true;
        float c0 = 0.f, c1 = 0.f, c2 = 0.f, c3 = 0.f, cs = 0.f;
        if (i < NKEEP) {
            u64 key = lk[i];
            u32 idx = ~(u32)(key & 0xFFFFFFFFull);
            cs = __uint_as_float((u32)(key >> 32));
            int px = idx / 12, a = idx - px * 12;
            float d0 = logit[(size_t)(12 + a * 4 + 0) * 4096 + px];
            float d1 = logit[(size_t)(12 + a * 4 + 1) * 4096 + px];
            float d2 = logit[(size_t)(12 + a * 4 + 2) * 4096 + px];
            float d3 = logit[(size_t)(12 + a * 4 + 3) * 4096 + px];
            int py = px >> 6, pxx = px & 63;
            double cx = pxx * 16.0 + 8.0, cy = py * 16.0 + 8.0;
            int si = a / 3, ri = a - si * 3;
            double scale = (double)(32 << si);
            double ratio = 0.5 * (double)(1 << ri);
            double sq = sqrt(ratio);
            double aw = scale * sq, ah = scale / sq;
            double xc = cx + (double)d0 * aw;
            double yc = cy + (double)d1 * ah;
            double wv = aw * exp((double)d2);
            double hv = ah * exp((double)d3);
            c0 = fminf(fmaxf((float)(xc - wv * 0.5), 0.f), W);
            c2 = fminf(fmaxf((float)(xc + wv * 0.5), 0.f), W);
            c1 = fminf(fmaxf((float)(yc - hv * 0.5), 0.f), H);
            c3 = fminf(fmaxf((float)(yc + hv * 0.5), 0.f), H);
            bool valid = ((c2 - c0) >= 16.f) && ((c3 - c1) >= 16.f) && (cs >= 0.05f);
            suppb = !valid;
        }
        cand5[i * 5 + 0] = c0;
        cand5[i * 5 + 1] = c1;
        cand5[i * 5 + 2] = c2;
        cand5[i * 5 + 3] = c3;
        cand5[i * 5 + 4] = cs;
        u64 bal = __ballot(suppb ? 1 : 0);
        if ((t & 63) == 0) suppws[i >> 6] = bal;
    }
}

// IoU > 0.7 bitmask, 64x64 tiles
__global__ __launch_bounds__(64) void k_mask(const float* __restrict__ cand5, u64* __restrict__ mask) {
    __shared__ float cb[64][5];
    int t = threadIdx.x;
    int bi = blockIdx.y, bj = blockIdx.x;
    int j = bj * 64 + t;
    {
        float b0 = cand5[j * 5 + 0], b1v = cand5[j * 5 + 1], b2v = cand5[j * 5 + 2], b3v = cand5[j * 5 + 3];
        cb[t][0] = b0; cb[t][1] = b1v; cb[t][2] = b2v; cb[t][3] = b3v;
        cb[t][4] = (b2v - b0) * (b3v - b1v);
    }
    __syncthreads();
    int i = bi * 64 + t;
    float r0 = cand5[i * 5 + 0], r1 = cand5[i * 5 + 1], r2 = cand5[i * 5 + 2], r3 = cand5[i * 5 + 3];
    float ra = (r2 - r0) * (r3 - r1);
    u64 bits = 0ull;
#pragma unroll 4
    for (int c = 0; c < 64; c++) {
        float lx = fmaxf(r0, cb[c][0]);
        float ly = fmaxf(r1, cb[c][1]);
        float rx = fminf(r2, cb[c][2]);
        float ry = fminf(r3, cb[c][3]);
        float w = fmaxf(rx - lx, 0.f);
        float h = fmaxf(ry - ly, 0.f);
        float inter = w * h;
        float iou = inter / fmaxf(ra + cb[c][4] - inter, 1e-6f);
        if (iou > 0.7f) bits |= (1ull << c);
    }
    mask[(size_t)i * 32 + bj] = bits;
}

// single-wave greedy NMS scan with depth-8 prefetch; writes first <=300 kept rows
__global__ __launch_bounds__(64) void k_scan(const u64* __restrict__ mask, const float* __restrict__ cand5,
                                             const u64* __restrict__ suppws, float* __restrict__ out) {
    int lane = threadIdx.x;
    u64 supp = (lane < 32) ? suppws[lane] : 0ull;
    u64 bufA[8], bufB[8];
    float dA[8], dB[8];
#pragma unroll
    for (int k = 0; k < 8; k++) {
        bufA[k] = (lane < 32) ? mask[(size_t)k * 32 + lane] : 0ull;
        dA[k] = (lane < 5) ? cand5[k * 5 + lane] : 0.f;
    }
    int kcount = 0;
    for (int gq = 0; gq < 256; gq++) {
        int base = gq * 8;
        if (gq < 255) {
            int nb = base + 8;
#pragma unroll
            for (int k = 0; k < 8; k++) {
                bufB[k] = (lane < 32) ? mask[(size_t)(nb + k) * 32 + lane] : 0ull;
                dB[k] = (lane < 5) ? cand5[(nb + k) * 5 + lane] : 0.f;
            }
        }
        int w = gq >> 3;
        u64 cur = __shfl(supp, w);
#pragma unroll
        for (int k = 0; k < 8; k++) {
            int i = base + k;
            if (i < NKEEP && !((cur >> (i & 63)) & 1ull)) {
                if (kcount < NTOPK) {
                    if (lane < 5) out[kcount * 5 + lane] = dA[k];
                    kcount++;
                }
                supp |= bufA[k];
                cur |= __shfl(bufA[k], w);
            }
        }
        if (kcount >= NTOPK) return;
#pragma unroll
        for (int k = 0; k < 8; k++) { bufA[k] = bufB[k]; dA[k] = dB[k]; }
    }
}

extern "C" void kernel_launch(void* const* d_in, const int* in_sizes, int n_in,
                              void* d_out, int out_size, void* d_ws, size_t ws_size,
                              hipStream_t stream) {
    (void)in_sizes; (void)n_in; (void)out_size;
    const float* fx = (const float*)d_in[0];
    const float* w1 = (const float*)d_in[1];
    const float* b1 = (const float*)d_in[2];
    const float* w2 = (const float*)d_in[3];
    const float* b2 = (const float*)d_in[4];
    const float* w3 = (const float*)d_in[5];
    const float* b3 = (const float*)d_in[6];
    const int* imh = (const int*)d_in[7];
    const int* imw = (const int*)d_in[8];

    char* ws = (char*)d_ws;
    float*  pacc   = (float*)(ws + OFF_PACC);
    float*  logit  = (float*)(ws + OFF_LOG);
    float*  scores = (float*)(ws + OFF_SCORES);
    u32*    hist   = (u32*)(ws + OFF_HIST);
    u64*    keys   = (u64*)(ws + OFF_KEYS);
    float*  cand5  = (float*)(ws + OFF_CAND5);
    u64*    mask   = (u64*)(ws + OFF_MASK);
    u32*    misc   = (u32*)(ws + OFF_MISC);
    u64*    suppws = (u64*)(ws + OFF_MISC + 64);
    uint4*  preW   = (uint4*)(ws + OFF_PREW);
    float*  out    = (float*)d_out;

    k_init<<<256, 256, 0, stream>>>(hist, keys, misc, out);
    if (ws_size >= WS_NEED) {
        k_splitw<<<dim3(32, 8, 2), 256, 0, stream>>>(w1, preW);
        k_conv1m<<<512, 512, 0, stream>>>(fx, preW, pacc);
    } else {
        k_conv1m_fb<<<512, 512, 0, stream>>>(fx, w1, pacc);
    }
    k_conv23f<<<64, 256, 0, stream>>>(pacc, b1, w2, b2, w3, b3, logit);
    k_scores<<<192, 256, 0, stream>>>(logit, scores, hist);
    k_scanhist<<<1, 256, 0, stream>>>(hist, misc);
    k_compact<<<192, 256, 0, stream>>>(scores, misc, keys);
    k_sort<<<1, 1024, 0, stream>>>(keys, logit, imh, imw, cand5, suppws);
    k_mask<<<dim3(32, 32), 64, 0, stream>>>(cand5, mask);
    k_scan<<<1, 64, 0, stream>>>(mask, cand5, suppws, out);
}

// Round 13
// 497.810 us; speedup vs baseline: 1.0807x; 1.0807x over previous
//
#include <hip/hip_runtime.h>
#include <math.h>

typedef unsigned int u32;
typedef unsigned long long u64;
typedef unsigned short u16;

typedef float f32x16 __attribute__((ext_vector_type(16)));
typedef short bf16x8 __attribute__((ext_vector_type(8)));

#define A_TOTAL 49152
#define NKEEP 2000
#define NTOPK 300
#define SORTN 4096

// ws layout (bytes)
#define OFF_PACC   0u            // [2][512][4096] f32 = 16,777,216 (conv1 kh-partials)
#define OFF_SCORES 16777216u     // 49152 f32
#define OFF_HIST   16973824u     // 65536 u32
#define OFF_KEYS   17235968u     // 4096 u64
#define OFF_CAND5  17268736u     // 2048*5 f32
#define OFF_MASK   17309696u     // 2048*32 u64
#define OFF_MISC   17833984u     // [0]=counter,[1]=B1 ; +64B: suppws u64[32]
#define OFF_PREW   17838080u     // [2kh][8yb][32c][3s][1152 units x 16B] = 28,311,552
#define OFF_POX    17838080u     // OVERLAYS preW (dead after conv1m): [60][4][4096] f64 = 7,864,320
#define WS_NEED    46149632ull

__global__ __launch_bounds__(256) void k_init(u32* __restrict__ hist, u64* __restrict__ keys,
                                              u32* __restrict__ misc, float* __restrict__ out) {
    int t = blockIdx.x * 256 + threadIdx.x;
    if (t < 65536) hist[t] = 0u;
    if (t < SORTN) keys[t] = 0ull;
    if (t < NTOPK * 5) out[t] = 0.f;
    if (t == 0) misc[0] = 0u;
}

// ---------- bf16 split helpers (all RNE — R7/R9/R11-validated numerics, LOCKED) ----------
__device__ __forceinline__ u16 f2bf(float v) {
    u32 u = __float_as_uint(v);
    return (u16)((u + 0x7FFFu + ((u >> 16) & 1u)) >> 16);
}
__device__ __forceinline__ float bf2f(u16 h) { return __uint_as_float(((u32)h) << 16); }
__device__ __forceinline__ void split3(float v, u16& h, u16& m, u16& l) {
    h = f2bf(v);
    float r1 = v - bf2f(h);
    m = f2bf(r1);
    float r2 = r1 - bf2f(m);
    l = f2bf(r2);
}
__device__ __forceinline__ bf16x8 ldsfrag(const u16* p) {
    const u64* q = (const u64*)p;
    union { u64 w[2]; bf16x8 v; } x;
    x.w[0] = q[0];
    x.w[1] = q[1];
    return x.v;
}
__device__ __forceinline__ void gll16(const void* g, void* l) {
    __builtin_amdgcn_global_load_lds((const __attribute__((address_space(1))) void*)g,
                                     (__attribute__((address_space(3))) void*)l, 16, 0, 0);
}
__device__ __forceinline__ void gll4(const void* g, void* l) {
    __builtin_amdgcn_global_load_lds((const __attribute__((address_space(1))) void*)g,
                                     (__attribute__((address_space(3))) void*)l, 4, 0, 0);
}

// Pre-split w1 -> preW bf16 triples in conv1m's exact LDS order (R12 coalesced version).
__global__ __launch_bounds__(256) void k_splitw(const float* __restrict__ w1, uint4* __restrict__ preW) {
    __shared__ __align__(16) u16 sW[3 * 9216];   // [s][((tap*2+g)*64+co)*8 + ci&7]
    const int tid = threadIdx.x;
    const int c = blockIdx.x;
    const int yb = blockIdx.y;
    const int kh = blockIdx.z;
    const float* base = w1 + (size_t)(yb * 64) * 9216 + (size_t)(kh * 512 + c * 16) * 9;
#pragma unroll
    for (int j = 0; j < 36; j++) {
        int e = tid + j * 256;           // 0..9215 = 64co x 144 (ci*9+tap)
        int co = e / 144, r = e - co * 144;
        int ci = r / 9, tap = r - ci * 9;
        float v = base[(size_t)co * 9216 + r];
        u16 h, m, l;
        split3(v, h, m, l);
        int li = ((tap * 2 + (ci >> 3)) * 64 + co) * 8 + (ci & 7);
        sW[li] = h; sW[9216 + li] = m; sW[18432 + li] = l;
    }
    __syncthreads();
    const uint4* sw4 = (const uint4*)sW;         // 3456 units
    uint4* dst = preW + (size_t)(((kh * 8 + yb) * 32 + c) * 3) * 1152;
#pragma unroll
    for (int j = 0; j < 14; j++) {
        int e = tid + j * 256;
        if (e < 3456) dst[e] = sw4[e];
    }
}

// conv1 via MFMA bf16x3 splits, 6 terms — R11-validated verbatim.
__global__ __launch_bounds__(512) void k_conv1m(const float* __restrict__ fx, const uint4* __restrict__ preW,
                                                float* __restrict__ pacc) {
    __shared__ __align__(16) u16 sA[3 * 9216];
    __shared__ __align__(16) u16 sB[3 * 3600];
    u32* const sB32 = (u32*)sB;
    const int tid = threadIdx.x;
    const int lane = tid & 63;
    const int wid = tid >> 6;
    const int cgw = wid >> 2;
    const int pgw = wid & 3;
    const int n = lane & 31;
    const int g = lane >> 5;
    const int bid = blockIdx.x;
    const int yb = bid & 7;
    const int rest = bid >> 3;
    const int bpx = rest & 31;
    const int kh = rest >> 5;
    const int y0 = (bpx >> 2) * 8, x0 = (bpx & 3) * 16;
    const int ci_base = kh * 512;

    int fgp[3], flp[3];
    bool wrp[3], ldp[3];
#pragma unroll
    for (int j = 0; j < 3; j++) {
        int p = tid + j * 512;
        bool wr = p < 1440;
        int a = p / 180, rem = p - a * 180;
        int hy = rem / 18, hx = rem - hy * 18;
        int gy = y0 + hy - 1, gx = x0 + hx - 1;
        bool ok = wr && gy >= 0 && gy < 64 && gx >= 0 && gx < 64;
        wrp[j] = wr;
        ldp[j] = ok;
        fgp[j] = ok ? ((2 * a) * 4096 + gy * 64 + gx) : 0;
        flp[j] = wr ? (rem * 10 + a) : 0;
    }

    f32x16 acc;
    double accD[16];
#pragma unroll
    for (int i = 0; i < 16; i++) { acc[i] = 0.f; accD[i] = 0.0; }

    float pA0[3], pA1[3], pB0[3], pB1[3];
    {
        const float* f0 = fx + (size_t)ci_base * 4096;
        const float* f1 = fx + (size_t)(ci_base + 16) * 4096;
#pragma unroll
        for (int j = 0; j < 3; j++) {
            pA0[j] = ldp[j] ? f0[fgp[j]] : 0.f;
            pA1[j] = ldp[j] ? f0[fgp[j] + 4096] : 0.f;
            pB0[j] = ldp[j] ? f1[fgp[j]] : 0.f;
            pB1[j] = ldp[j] ? f1[fgp[j] + 4096] : 0.f;
        }
    }
    const char* wbase = (const char*)preW + (size_t)((kh * 8 + yb) * 32) * 3 * 18432;
    char* const sAc = (char*)sA;

#pragma unroll 1
    for (int c = 0; c < 32; c++) {
        __syncthreads();
        const char* wsrc = wbase + (size_t)c * 3 * 18432;
#pragma unroll
        for (int s = 0; s < 3; s++) {
            gll16(wsrc + s * 18432 + tid * 16,         sAc + s * 18432 + wid * 1024);
            gll16(wsrc + s * 18432 + 8192 + tid * 16,  sAc + s * 18432 + 8192 + wid * 1024);
            gll4 (wsrc + s * 18432 + 16384 + tid * 4,  sAc + s * 18432 + 16384 + wid * 256);
        }
#pragma unroll
        for (int j = 0; j < 3; j++) {
            if (wrp[j]) {
                u16 h0, m0, l0, h1, m1, l1;
                split3(pA0[j], h0, m0, l0);
                split3(pA1[j], h1, m1, l1);
                sB32[flp[j]] = (u32)h0 | ((u32)h1 << 16);
                sB32[1800 + flp[j]] = (u32)m0 | ((u32)m1 << 16);
                sB32[3600 + flp[j]] = (u32)l0 | ((u32)l1 << 16);
            }
        }
        __syncthreads();
#pragma unroll
        for (int j = 0; j < 3; j++) { pA0[j] = pB0[j]; pA1[j] = pB1[j]; }
        if (c < 30) {
            const float* fp = fx + (size_t)(ci_base + (c + 2) * 16) * 4096;
#pragma unroll
            for (int j = 0; j < 3; j++) {
                pB0[j] = ldp[j] ? fp[fgp[j]] : 0.f;
                pB1[j] = ldp[j] ? fp[fgp[j] + 4096] : 0.f;
            }
        }

#pragma unroll 1
        for (int dy = 0; dy < 3; dy++) {
#pragma unroll
            for (int dx = 0; dx < 3; dx++) {
                const int tap = dy * 3 + dx;
                const int aoff = ((tap * 2 + g) * 64 + cgw * 32 + n) * 8;
                bf16x8 ah = ldsfrag(&sA[aoff]);
                bf16x8 am = ldsfrag(&sA[9216 + aoff]);
                bf16x8 al = ldsfrag(&sA[18432 + aoff]);
                const int loc = (pgw * 2 + (n >> 4) + dy) * 18 + (n & 15) + dx;
                const int boff = loc * 20 + g * 8;
                bf16x8 bh = ldsfrag(&sB[boff]);
                bf16x8 bm = ldsfrag(&sB[3600 + boff]);
                bf16x8 bl = ldsfrag(&sB[7200 + boff]);
                acc = __builtin_amdgcn_mfma_f32_32x32x16_bf16(ah, bh, acc, 0, 0, 0);
                acc = __builtin_amdgcn_mfma_f32_32x32x16_bf16(ah, bm, acc, 0, 0, 0);
                acc = __builtin_amdgcn_mfma_f32_32x32x16_bf16(am, bh, acc, 0, 0, 0);
                acc = __builtin_amdgcn_mfma_f32_32x32x16_bf16(ah, bl, acc, 0, 0, 0);
                acc = __builtin_amdgcn_mfma_f32_32x32x16_bf16(am, bm, acc, 0, 0, 0);
                acc = __builtin_amdgcn_mfma_f32_32x32x16_bf16(al, bh, acc, 0, 0, 0);
            }
#pragma unroll
            for (int i = 0; i < 16; i++) { accD[i] += (double)acc[i]; acc[i] = 0.f; }
        }
    }

    {
        int p = pgw * 32 + n;
        int py = p >> 4, pxx = p & 15;
        int gp = (y0 + py) * 64 + x0 + pxx;
        const int row_hi = 4 * g;
#pragma unroll
        for (int rg = 0; rg < 16; rg++) {
            int co = yb * 64 + cgw * 32 + (rg & 3) + 8 * (rg >> 2) + row_hi;
            pacc[(size_t)kh * 2097152 + (size_t)co * 4096 + gp] = (float)accD[rg];
        }
    }
}

// Fallback (ws too small for preW): runtime-split kernel, R9/R11 verbatim.
__global__ __launch_bounds__(512) void k_conv1m_fb(const float* __restrict__ fx, const float* __restrict__ w1,
                                                   float* __restrict__ pacc) {
    __shared__ u16 sA[3 * 9472];
    __shared__ u16 sB[3 * 3600];
    u32* const sA32 = (u32*)sA;
    const int tid = threadIdx.x;
    const int lane = tid & 63;
    const int wid = tid >> 6;
    const int cgw = wid >> 2;
    const int pgw = wid & 3;
    const int n = lane & 31;
    const int g = lane >> 5;
    const int bid = blockIdx.x;
    const int yb = bid & 7;
    const int rest = bid >> 3;
    const int bpx = rest & 31;
    const int kh = rest >> 5;
    const int y0 = (bpx >> 2) * 8, x0 = (bpx & 3) * 16;
    const int co0 = yb * 64;
    const int ci_base = kh * 512;

    int wgp[9], wlp[9];
#pragma unroll
    for (int j = 0; j < 9; j++) {
        int p = tid + j * 512;
        int co = p / 72, q = p - co * 72;
        int a = q & 7, b = q >> 3;
        wgp[j] = co * 9216 + (2 * a) * 9 + b;
        wlp[j] = co * 74 + b * 8 + a;
    }
    int fg0[6], fl[6];
#pragma unroll
    for (int j = 0; j < 6; j++) {
        int idx = tid + j * 512;
        bool wr = idx < 2880;
        int ci = idx / 180, rem = idx - ci * 180;
        int hy = rem / 18, hx = rem - hy * 18;
        int gy = y0 + hy - 1, gx = x0 + hx - 1;
        bool ok = wr && gy >= 0 && gy < 64 && gx >= 0 && gx < 64;
        fg0[j] = ok ? (ci * 4096 + gy * 64 + gx) : -1;
        fl[j] = wr ? (rem * 20 + ci) : -1;
    }

    f32x16 acc;
    double accD[16];
#pragma unroll
    for (int i = 0; i < 16; i++) { acc[i] = 0.f; accD[i] = 0.0; }

    float pw[18], pfA[6], pfB[6];
    {
        const float* wp = w1 + (size_t)co0 * 9216 + (size_t)ci_base * 9;
#pragma unroll
        for (int j = 0; j < 9; j++) { pw[2 * j] = wp[wgp[j]]; pw[2 * j + 1] = wp[wgp[j] + 9]; }
        const float* f0 = fx + (size_t)ci_base * 4096;
        const float* f1 = fx + (size_t)(ci_base + 16) * 4096;
#pragma unroll
        for (int j = 0; j < 6; j++) {
            pfA[j] = (fg0[j] >= 0) ? f0[fg0[j]] : 0.f;
            pfB[j] = (fg0[j] >= 0) ? f1[fg0[j]] : 0.f;
        }
    }

#pragma unroll 1
    for (int c = 0; c < 32; c++) {
        __syncthreads();
#pragma unroll
        for (int j = 0; j < 9; j++) {
            u16 h0, m0, l0, h1, m1, l1;
            split3(pw[2 * j], h0, m0, l0);
            split3(pw[2 * j + 1], h1, m1, l1);
            sA32[wlp[j]] = (u32)h0 | ((u32)h1 << 16);
            sA32[4736 + wlp[j]] = (u32)m0 | ((u32)m1 << 16);
            sA32[9472 + wlp[j]] = (u32)l0 | ((u32)l1 << 16);
        }
#pragma unroll
        for (int j = 0; j < 6; j++) {
            if (fl[j] >= 0) {
                u16 h, m, l;
                split3(pfA[j], h, m, l);
                sB[fl[j]] = h; sB[3600 + fl[j]] = m; sB[7200 + fl[j]] = l;
            }
        }
        __syncthreads();
        if (c < 31) {
            const float* wp = w1 + (size_t)co0 * 9216 + (size_t)(ci_base + (c + 1) * 16) * 9;
#pragma unroll
            for (int j = 0; j < 9; j++) { pw[2 * j] = wp[wgp[j]]; pw[2 * j + 1] = wp[wgp[j] + 9]; }
        }
#pragma unroll
        for (int j = 0; j < 6; j++) pfA[j] = pfB[j];
        if (c < 30) {
            const float* fp = fx + (size_t)(ci_base + (c + 2) * 16) * 4096;
#pragma unroll
            for (int j = 0; j < 6; j++) pfB[j] = (fg0[j] >= 0) ? fp[fg0[j]] : 0.f;
        }

#pragma unroll 1
        for (int dy = 0; dy < 3; dy++) {
#pragma unroll
            for (int dx = 0; dx < 3; dx++) {
                const int tap = dy * 3 + dx;
                const int aoff = (cgw * 32 + n) * 148 + tap * 16 + g * 8;
                bf16x8 ah = ldsfrag(&sA[aoff]);
                bf16x8 am = ldsfrag(&sA[9472 + aoff]);
                bf16x8 al = ldsfrag(&sA[18944 + aoff]);
                const int loc = (pgw * 2 + (n >> 4) + dy) * 18 + (n & 15) + dx;
                const int boff = loc * 20 + g * 8;
                bf16x8 bh = ldsfrag(&sB[boff]);
                bf16x8 bm = ldsfrag(&sB[3600 + boff]);
                bf16x8 bl = ldsfrag(&sB[7200 + boff]);
                acc = __builtin_amdgcn_mfma_f32_32x32x16_bf16(ah, bh, acc, 0, 0, 0);
                acc = __builtin_amdgcn_mfma_f32_32x32x16_bf16(ah, bm, acc, 0, 0, 0);
                acc = __builtin_amdgcn_mfma_f32_32x32x16_bf16(am, bh, acc, 0, 0, 0);
                acc = __builtin_amdgcn_mfma_f32_32x32x16_bf16(ah, bl, acc, 0, 0, 0);
                acc = __builtin_amdgcn_mfma_f32_32x32x16_bf16(am, bm, acc, 0, 0, 0);
                acc = __builtin_amdgcn_mfma_f32_32x32x16_bf16(al, bh, acc, 0, 0, 0);
            }
#pragma unroll
            for (int i = 0; i < 16; i++) { accD[i] += (double)acc[i]; acc[i] = 0.f; }
        }
    }

    {
        int p = pgw * 32 + n;
        int py = p >> 4, pxx = p & 15;
        int gp = (y0 + py) * 64 + x0 + pxx;
        const int row_hi = 4 * g;
#pragma unroll
        for (int rg = 0; rg < 16; rg++) {
            int co = co0 + cgw * 32 + (rg & 3) + 8 * (rg >> 2) + row_hi;
            pacc[(size_t)kh * 2097152 + (size_t)co * 4096 + gp] = (float)accD[rg];
        }
    }
}

// 1x1 convs, R11's validated 256-block shape (64 px-tiles x 4 ci-quarters), with k_comb
// FUSED into x-staging: xs = relu(f32(p0+p1+b1)) — bitwise identical to old k_comb.
// f64 ci-quarter partials to pox (same order as R11); bias added later (scores/sort).
__global__ __launch_bounds__(256) void k_conv23q(const float* __restrict__ pacc,
                                                 const float* __restrict__ b1,
                                                 const float* __restrict__ w2, const float* __restrict__ w3,
                                                 double* __restrict__ pox) {
    __shared__ float xs[32 * 64];     // [ci][px]
    __shared__ float wsh[60 * 128];   // [o][ci]
    const int tid = threadIdx.x;
    const int px0 = blockIdx.x * 64;
    const int cib = blockIdx.y * 128;
    const int px = tid & 63;
    const int og = tid >> 6;          // 0..3 -> o = og*15 + j

#pragma unroll
    for (int k = 0; k < 30; k++) {
        int e = tid + k * 256;
        int o = e >> 7, ci = e & 127;
        float wv = (o < 12) ? w2[o * 512 + cib + ci] : w3[(size_t)(o - 12) * 512 + cib + ci];
        wsh[o * 128 + ci] = wv;
    }

    double acc[15];
#pragma unroll
    for (int j = 0; j < 15; j++) acc[j] = 0.0;

#pragma unroll 1
    for (int ch = 0; ch < 4; ch++) {
        __syncthreads();
#pragma unroll
        for (int k = 0; k < 8; k++) {
            int e = tid + k * 256;
            int ci = e >> 6, p = e & 63;
            int cig = cib + ch * 32 + ci;
            size_t gi = (size_t)cig * 4096 + px0 + p;
            double v = (double)pacc[gi] + (double)pacc[2097152 + gi] + (double)b1[cig];
            xs[ci * 64 + p] = fmaxf((float)v, 0.f);   // bitwise = old k_comb
        }
        __syncthreads();
#pragma unroll 1
        for (int ci = 0; ci < 32; ci++) {
            double xd = (double)xs[ci * 64 + px];
            const float* wrow = &wsh[ch * 32 + ci];
#pragma unroll
            for (int j = 0; j < 15; j++)
                acc[j] = fma(xd, (double)wrow[(og * 15 + j) * 128], acc[j]);
        }
    }
#pragma unroll
    for (int j = 0; j < 15; j++) {
        int o = og * 15 + j;
        pox[((size_t)o * 4 + blockIdx.y) * 4096 + px0 + px] = acc[j];
    }
}

// scores: combine ci-quarter partials (+b2, round f32 — same points as R11 k_boxes),
// f64 sigmoid, 16-bit-prefix histogram.
__global__ __launch_bounds__(256) void k_scores(const double* __restrict__ pox,
                                                const float* __restrict__ b2,
                                                float* __restrict__ scores, u32* __restrict__ hist) {
    int idx = blockIdx.x * 256 + threadIdx.x;
    if (idx >= A_TOTAL) return;
    int px = idx / 12, a = idx - px * 12;
    double t = 0.0;
#pragma unroll
    for (int q = 0; q < 4; q++) t += pox[((size_t)a * 4 + q) * 4096 + px];
    float o = (float)(t + (double)b2[a]);
    float s = (float)(1.0 / (1.0 + exp(-(double)o)));
    scores[idx] = s;
    atomicAdd(&hist[__float_as_uint(s) >> 16], 1u);
}

// find boundary bin B1 so that count(bins >= B1) >= 2000, count(bins > B1) < 2000
__global__ __launch_bounds__(256) void k_scanhist(const u32* __restrict__ hist, u32* __restrict__ misc) {
    __shared__ u32 csum[256];
    __shared__ u32 cb[256];
    __shared__ int s_cidx;
    __shared__ u32 s_cacc;
    int t = threadIdx.x;
    u32 sum = 0;
    const uint4* h4 = (const uint4*)(hist + t * 256);
    for (int j = 0; j < 64; j++) { uint4 v = h4[j]; sum += v.x + v.y + v.z + v.w; }
    csum[t] = sum;
    __syncthreads();
    if (t == 0) {
        u32 acc = 0;
        int c = 255;
        for (; c > 0; c--) {
            if (acc + csum[c] >= NKEEP) break;
            acc += csum[c];
        }
        s_cidx = c;
        s_cacc = acc;
    }
    __syncthreads();
    cb[t] = hist[s_cidx * 256 + t];
    __syncthreads();
    if (t == 0) {
        u32 acc = s_cacc;
        int b = 255;
        for (; b > 0; b--) {
            acc += cb[b];
            if (acc >= NKEEP) break;
        }
        misc[1] = (u32)(s_cidx * 256 + b);
    }
}

__global__ __launch_bounds__(256) void k_compact(const float* __restrict__ scores, u32* __restrict__ misc,
                                                 u64* __restrict__ keys) {
    int idx = blockIdx.x * 256 + threadIdx.x;
    if (idx >= A_TOTAL) return;
    u32 bits = __float_as_uint(scores[idx]);
    if ((bits >> 16) >= misc[1]) {
        u32 slot = atomicAdd(&misc[0], 1u);
        if (slot < SORTN) keys[slot] = ((u64)bits << 32) | (u64)(~(u32)idx);
    }
}

// bitonic sort 4096 keys DESC; epilogue decodes only the top-2000 boxes from pox
// partials (+b3, round f32 — identical combine order/rounding to R11 k_boxes) + suppws.
__global__ __launch_bounds__(1024) void k_sort(const u64* __restrict__ keys, const double* __restrict__ pox,
                                               const float* __restrict__ b3,
                                               const int* __restrict__ imh, const int* __restrict__ imw,
                                               float* __restrict__ cand5, u64* __restrict__ suppws) {
    __shared__ u64 lk[SORTN];
    int t = threadIdx.x;
#pragma unroll
    for (int r = 0; r < 4; r++) lk[r * 1024 + t] = keys[r * 1024 + t];
    for (int kk = 2; kk <= SORTN; kk <<= 1) {
        for (int jj = kk >> 1; jj > 0; jj >>= 1) {
            __syncthreads();
#pragma unroll
            for (int rep = 0; rep < 4; rep++) {
                int i = rep * 1024 + t;
                int ixj = i ^ jj;
                if (ixj > i) {
                    u64 a = lk[i], b = lk[ixj];
                    bool sw = ((i & kk) == 0) ? (a < b) : (a > b);
                    if (sw) { lk[i] = b; lk[ixj] = a; }
                }
            }
        }
    }
    __syncthreads();
    float W = (float)imw[0], H = (float)imh[0];
#pragma unroll
    for (int rep = 0; rep < 2; rep++) {
        int i = rep * 1024 + t;
        bool suppb = true;
        float c0 = 0.f, c1 = 0.f, c2 = 0.f, c3 = 0.f, cs = 0.f;
        if (i < NKEEP) {
            u64 key = lk[i];
            u32 idx = ~(u32)(key & 0xFFFFFFFFull);
            cs = __uint_as_float((u32)(key >> 32));
            int px = idx / 12, a = idx - px * 12;
            float d[4];
#pragma unroll
            for (int c = 0; c < 4; c++) {
                int oo = 12 + a * 4 + c;
                double u = 0.0;
#pragma unroll
                for (int q = 0; q < 4; q++) u += pox[((size_t)oo * 4 + q) * 4096 + px];
                d[c] = (float)(u + (double)b3[a * 4 + c]);
            }
            int py = px >> 6, pxx = px & 63;
            double cx = pxx * 16.0 + 8.0, cy = py * 16.0 + 8.0;
            int si = a / 3, ri = a - si * 3;
            double scale = (double)(32 << si);
            double ratio = 0.5 * (double)(1 << ri);
            double sq = sqrt(ratio);
            double aw = scale * sq, ah = scale / sq;
            double xc = cx + (double)d[0] * aw;
            double yc = cy + (double)d[1] * ah;
            double wv = aw * exp((double)d[2]);
            double hv = ah * exp((double)d[3]);
            c0 = fminf(fmaxf((float)(xc - wv * 0.5), 0.f), W);
            c2 = fminf(fmaxf((float)(xc + wv * 0.5), 0.f), W);
            c1 = fminf(fmaxf((float)(yc - hv * 0.5), 0.f), H);
            c3 = fminf(fmaxf((float)(yc + hv * 0.5), 0.f), H);
            bool valid = ((c2 - c0) >= 16.f) && ((c3 - c1) >= 16.f) && (cs >= 0.05f);
            suppb = !valid;
        }
        cand5[i * 5 + 0] = c0;
        cand5[i * 5 + 1] = c1;
        cand5[i * 5 + 2] = c2;
        cand5[i * 5 + 3] = c3;
        cand5[i * 5 + 4] = cs;
        u64 bal = __ballot(suppb ? 1 : 0);
        if ((t & 63) == 0) suppws[i >> 6] = bal;
    }
}

// IoU > 0.7 bitmask, 64x64 tiles
__global__ __launch_bounds__(64) void k_mask(const float* __restrict__ cand5, u64* __restrict__ mask) {
    __shared__ float cb[64][5];
    int t = threadIdx.x;
    int bi = blockIdx.y, bj = blockIdx.x;
    int j = bj * 64 + t;
    {
        float b0 = cand5[j * 5 + 0], b1v = cand5[j * 5 + 1], b2v = cand5[j * 5 + 2], b3v = cand5[j * 5 + 3];
        cb[t][0] = b0; cb[t][1] = b1v; cb[t][2] = b2v; cb[t][3] = b3v;
        cb[t][4] = (b2v - b0) * (b3v - b1v);
    }
    __syncthreads();
    int i = bi * 64 + t;
    float r0 = cand5[i * 5 + 0], r1 = cand5[i * 5 + 1], r2 = cand5[i * 5 + 2], r3 = cand5[i * 5 + 3];
    float ra = (r2 - r0) * (r3 - r1);
    u64 bits = 0ull;
#pragma unroll 4
    for (int c = 0; c < 64; c++) {
        float lx = fmaxf(r0, cb[c][0]);
        float ly = fmaxf(r1, cb[c][1]);
        float rx = fminf(r2, cb[c][2]);
        float ry = fminf(r3, cb[c][3]);
        float w = fmaxf(rx - lx, 0.f);
        float h = fmaxf(ry - ly, 0.f);
        float inter = w * h;
        float iou = inter / fmaxf(ra + cb[c][4] - inter, 1e-6f);
        if (iou > 0.7f) bits |= (1ull << c);
    }
    mask[(size_t)i * 32 + bj] = bits;
}

// single-wave greedy NMS scan with depth-8 prefetch; writes first <=300 kept rows
__global__ __launch_bounds__(64) void k_scan(const u64* __restrict__ mask, const float* __restrict__ cand5,
                                             const u64* __restrict__ suppws, float* __restrict__ out) {
    int lane = threadIdx.x;
    u64 supp = (lane < 32) ? suppws[lane] : 0ull;
    u64 bufA[8], bufB[8];
    float dA[8], dB[8];
#pragma unroll
    for (int k = 0; k < 8; k++) {
        bufA[k] = (lane < 32) ? mask[(size_t)k * 32 + lane] : 0ull;
        dA[k] = (lane < 5) ? cand5[k * 5 + lane] : 0.f;
    }
    int kcount = 0;
    for (int gq = 0; gq < 256; gq++) {
        int base = gq * 8;
        if (gq < 255) {
            int nb = base + 8;
#pragma unroll
            for (int k = 0; k < 8; k++) {
                bufB[k] = (lane < 32) ? mask[(size_t)(nb + k) * 32 + lane] : 0ull;
                dB[k] = (lane < 5) ? cand5[(nb + k) * 5 + lane] : 0.f;
            }
        }
        int w = gq >> 3;
        u64 cur = __shfl(supp, w);
#pragma unroll
        for (int k = 0; k < 8; k++) {
            int i = base + k;
            if (i < NKEEP && !((cur >> (i & 63)) & 1ull)) {
                if (kcount < NTOPK) {
                    if (lane < 5) out[kcount * 5 + lane] = dA[k];
                    kcount++;
                }
                supp |= bufA[k];
                cur |= __shfl(bufA[k], w);
            }
        }
        if (kcount >= NTOPK) return;
#pragma unroll
        for (int k = 0; k < 8; k++) { bufA[k] = bufB[k]; dA[k] = dB[k]; }
    }
}

extern "C" void kernel_launch(void* const* d_in, const int* in_sizes, int n_in,
                              void* d_out, int out_size, void* d_ws, size_t ws_size,
                              hipStream_t stream) {
    (void)in_sizes; (void)n_in; (void)out_size;
    const float* fx = (const float*)d_in[0];
    const float* w1 = (const float*)d_in[1];
    const float* b1 = (const float*)d_in[2];
    const float* w2 = (const float*)d_in[3];
    const float* b2 = (const float*)d_in[4];
    const float* w3 = (const float*)d_in[5];
    const float* b3 = (const float*)d_in[6];
    const int* imh = (const int*)d_in[7];
    const int* imw = (const int*)d_in[8];

    char* ws = (char*)d_ws;
    float*  pacc   = (float*)(ws + OFF_PACC);
    float*  scores = (float*)(ws + OFF_SCORES);
    u32*    hist   = (u32*)(ws + OFF_HIST);
    u64*    keys   = (u64*)(ws + OFF_KEYS);
    float*  cand5  = (float*)(ws + OFF_CAND5);
    u64*    mask   = (u64*)(ws + OFF_MASK);
    u32*    misc   = (u32*)(ws + OFF_MISC);
    u64*    suppws = (u64*)(ws + OFF_MISC + 64);
    uint4*  preW   = (uint4*)(ws + OFF_PREW);
    double* pox    = (double*)(ws + OFF_POX);    // overlays preW (dead after conv1m)
    float*  out    = (float*)d_out;

    k_init<<<256, 256, 0, stream>>>(hist, keys, misc, out);
    if (ws_size >= WS_NEED) {
        k_splitw<<<dim3(32, 8, 2), 256, 0, stream>>>(w1, preW);
        k_conv1m<<<512, 512, 0, stream>>>(fx, preW, pacc);
    } else {
        k_conv1m_fb<<<512, 512, 0, stream>>>(fx, w1, pacc);
    }
    k_conv23q<<<dim3(64, 4), 256, 0, stream>>>(pacc, b1, w2, w3, pox);
    k_scores<<<192, 256, 0, stream>>>(pox, b2, scores, hist);
    k_scanhist<<<1, 256, 0, stream>>>(hist, misc);
    k_compact<<<192, 256, 0, stream>>>(scores, misc, keys);
    k_sort<<<1, 1024, 0, stream>>>(keys, pox, b3, imh, imw, cand5, suppws);
    k_mask<<<dim3(32, 32), 64, 0, stream>>>(cand5, mask);
    k_scan<<<1, 64, 0, stream>>>(mask, cand5, suppws, out);
}

// Round 14
// 478.272 us; speedup vs baseline: 1.1248x; 1.0409x over previous
//
#include <hip/hip_runtime.h>
#include <math.h>

typedef unsigned int u32;
typedef unsigned long long u64;
typedef unsigned short u16;

typedef float f32x16 __attribute__((ext_vector_type(16)));
typedef short bf16x8 __attribute__((ext_vector_type(8)));

#define A_TOTAL 49152
#define NKEEP 2000
#define NTOPK 300
#define SORTN 4096

// ws layout (bytes)
#define OFF_PACC   0u            // [2][512][4096] f32 = 16,777,216 (conv1 kh-partials)
#define OFF_SCORES 16777216u     // 49152 f32
#define OFF_HIST   16973824u     // 65536 u32
#define OFF_KEYS   17235968u     // 4096 u64
#define OFF_CAND5  17268736u     // 2048*5 f32
#define OFF_MASK   17309696u     // 2048*32 u64
#define OFF_BOX4   17833984u     // 4096*4 f32 slotted boxes = 65,536
#define OFF_MISC   17899520u     // [0]=counter,[1]=B1 ; +64B: suppws u64[32]
#define OFF_PREW   17903616u     // [2kh][8yb][32c][3s][1152 units x 16B] = 28,311,552
#define OFF_POX    17903616u     // OVERLAYS preW (dead after conv1m): [60][4][4096] f64 = 7,864,320
#define WS_NEED    46215168ull

__global__ __launch_bounds__(256) void k_init(u32* __restrict__ hist, u64* __restrict__ keys,
                                              u32* __restrict__ misc, float* __restrict__ out) {
    int t = blockIdx.x * 256 + threadIdx.x;
    if (t < 65536) hist[t] = 0u;
    if (t < SORTN) keys[t] = 0ull;
    if (t < NTOPK * 5) out[t] = 0.f;
    if (t == 0) misc[0] = 0u;
}

// ---------- bf16 split helpers (all RNE — R7/R9/R11-validated numerics, LOCKED) ----------
__device__ __forceinline__ u16 f2bf(float v) {
    u32 u = __float_as_uint(v);
    return (u16)((u + 0x7FFFu + ((u >> 16) & 1u)) >> 16);
}
__device__ __forceinline__ float bf2f(u16 h) { return __uint_as_float(((u32)h) << 16); }
__device__ __forceinline__ void split3(float v, u16& h, u16& m, u16& l) {
    h = f2bf(v);
    float r1 = v - bf2f(h);
    m = f2bf(r1);
    float r2 = r1 - bf2f(m);
    l = f2bf(r2);
}
__device__ __forceinline__ bf16x8 ldsfrag(const u16* p) {
    const u64* q = (const u64*)p;
    union { u64 w[2]; bf16x8 v; } x;
    x.w[0] = q[0];
    x.w[1] = q[1];
    return x.v;
}
__device__ __forceinline__ void gll16(const void* g, void* l) {
    __builtin_amdgcn_global_load_lds((const __attribute__((address_space(1))) void*)g,
                                     (__attribute__((address_space(3))) void*)l, 16, 0, 0);
}
__device__ __forceinline__ void gll4(const void* g, void* l) {
    __builtin_amdgcn_global_load_lds((const __attribute__((address_space(1))) void*)g,
                                     (__attribute__((address_space(3))) void*)l, 4, 0, 0);
}

// Pre-split w1 -> preW bf16 triples in conv1m's exact LDS order (R12 coalesced version).
__global__ __launch_bounds__(256) void k_splitw(const float* __restrict__ w1, uint4* __restrict__ preW) {
    __shared__ __align__(16) u16 sW[3 * 9216];   // [s][((tap*2+g)*64+co)*8 + ci&7]
    const int tid = threadIdx.x;
    const int c = blockIdx.x;
    const int yb = blockIdx.y;
    const int kh = blockIdx.z;
    const float* base = w1 + (size_t)(yb * 64) * 9216 + (size_t)(kh * 512 + c * 16) * 9;
#pragma unroll
    for (int j = 0; j < 36; j++) {
        int e = tid + j * 256;           // 0..9215 = 64co x 144 (ci*9+tap)
        int co = e / 144, r = e - co * 144;
        int ci = r / 9, tap = r - ci * 9;
        float v = base[(size_t)co * 9216 + r];
        u16 h, m, l;
        split3(v, h, m, l);
        int li = ((tap * 2 + (ci >> 3)) * 64 + co) * 8 + (ci & 7);
        sW[li] = h; sW[9216 + li] = m; sW[18432 + li] = l;
    }
    __syncthreads();
    const uint4* sw4 = (const uint4*)sW;         // 3456 units
    uint4* dst = preW + (size_t)(((kh * 8 + yb) * 32 + c) * 3) * 1152;
#pragma unroll
    for (int j = 0; j < 14; j++) {
        int e = tid + j * 256;
        if (e < 3456) dst[e] = sw4[e];
    }
}

// conv1 via MFMA bf16x3 splits, 6 terms — R11-validated verbatim.
__global__ __launch_bounds__(512) void k_conv1m(const float* __restrict__ fx, const uint4* __restrict__ preW,
                                                float* __restrict__ pacc) {
    __shared__ __align__(16) u16 sA[3 * 9216];
    __shared__ __align__(16) u16 sB[3 * 3600];
    u32* const sB32 = (u32*)sB;
    const int tid = threadIdx.x;
    const int lane = tid & 63;
    const int wid = tid >> 6;
    const int cgw = wid >> 2;
    const int pgw = wid & 3;
    const int n = lane & 31;
    const int g = lane >> 5;
    const int bid = blockIdx.x;
    const int yb = bid & 7;
    const int rest = bid >> 3;
    const int bpx = rest & 31;
    const int kh = rest >> 5;
    const int y0 = (bpx >> 2) * 8, x0 = (bpx & 3) * 16;
    const int ci_base = kh * 512;

    int fgp[3], flp[3];
    bool wrp[3], ldp[3];
#pragma unroll
    for (int j = 0; j < 3; j++) {
        int p = tid + j * 512;
        bool wr = p < 1440;
        int a = p / 180, rem = p - a * 180;
        int hy = rem / 18, hx = rem - hy * 18;
        int gy = y0 + hy - 1, gx = x0 + hx - 1;
        bool ok = wr && gy >= 0 && gy < 64 && gx >= 0 && gx < 64;
        wrp[j] = wr;
        ldp[j] = ok;
        fgp[j] = ok ? ((2 * a) * 4096 + gy * 64 + gx) : 0;
        flp[j] = wr ? (rem * 10 + a) : 0;
    }

    f32x16 acc;
    double accD[16];
#pragma unroll
    for (int i = 0; i < 16; i++) { acc[i] = 0.f; accD[i] = 0.0; }

    float pA0[3], pA1[3], pB0[3], pB1[3];
    {
        const float* f0 = fx + (size_t)ci_base * 4096;
        const float* f1 = fx + (size_t)(ci_base + 16) * 4096;
#pragma unroll
        for (int j = 0; j < 3; j++) {
            pA0[j] = ldp[j] ? f0[fgp[j]] : 0.f;
            pA1[j] = ldp[j] ? f0[fgp[j] + 4096] : 0.f;
            pB0[j] = ldp[j] ? f1[fgp[j]] : 0.f;
            pB1[j] = ldp[j] ? f1[fgp[j] + 4096] : 0.f;
        }
    }
    const char* wbase = (const char*)preW + (size_t)((kh * 8 + yb) * 32) * 3 * 18432;
    char* const sAc = (char*)sA;

#pragma unroll 1
    for (int c = 0; c < 32; c++) {
        __syncthreads();
        const char* wsrc = wbase + (size_t)c * 3 * 18432;
#pragma unroll
        for (int s = 0; s < 3; s++) {
            gll16(wsrc + s * 18432 + tid * 16,         sAc + s * 18432 + wid * 1024);
            gll16(wsrc + s * 18432 + 8192 + tid * 16,  sAc + s * 18432 + 8192 + wid * 1024);
            gll4 (wsrc + s * 18432 + 16384 + tid * 4,  sAc + s * 18432 + 16384 + wid * 256);
        }
#pragma unroll
        for (int j = 0; j < 3; j++) {
            if (wrp[j]) {
                u16 h0, m0, l0, h1, m1, l1;
                split3(pA0[j], h0, m0, l0);
                split3(pA1[j], h1, m1, l1);
                sB32[flp[j]] = (u32)h0 | ((u32)h1 << 16);
                sB32[1800 + flp[j]] = (u32)m0 | ((u32)m1 << 16);
                sB32[3600 + flp[j]] = (u32)l0 | ((u32)l1 << 16);
            }
        }
        __syncthreads();
#pragma unroll
        for (int j = 0; j < 3; j++) { pA0[j] = pB0[j]; pA1[j] = pB1[j]; }
        if (c < 30) {
            const float* fp = fx + (size_t)(ci_base + (c + 2) * 16) * 4096;
#pragma unroll
            for (int j = 0; j < 3; j++) {
                pB0[j] = ldp[j] ? fp[fgp[j]] : 0.f;
                pB1[j] = ldp[j] ? fp[fgp[j] + 4096] : 0.f;
            }
        }

#pragma unroll 1
        for (int dy = 0; dy < 3; dy++) {
#pragma unroll
            for (int dx = 0; dx < 3; dx++) {
                const int tap = dy * 3 + dx;
                const int aoff = ((tap * 2 + g) * 64 + cgw * 32 + n) * 8;
                bf16x8 ah = ldsfrag(&sA[aoff]);
                bf16x8 am = ldsfrag(&sA[9216 + aoff]);
                bf16x8 al = ldsfrag(&sA[18432 + aoff]);
                const int loc = (pgw * 2 + (n >> 4) + dy) * 18 + (n & 15) + dx;
                const int boff = loc * 20 + g * 8;
                bf16x8 bh = ldsfrag(&sB[boff]);
                bf16x8 bm = ldsfrag(&sB[3600 + boff]);
                bf16x8 bl = ldsfrag(&sB[7200 + boff]);
                acc = __builtin_amdgcn_mfma_f32_32x32x16_bf16(ah, bh, acc, 0, 0, 0);
                acc = __builtin_amdgcn_mfma_f32_32x32x16_bf16(ah, bm, acc, 0, 0, 0);
                acc = __builtin_amdgcn_mfma_f32_32x32x16_bf16(am, bh, acc, 0, 0, 0);
                acc = __builtin_amdgcn_mfma_f32_32x32x16_bf16(ah, bl, acc, 0, 0, 0);
                acc = __builtin_amdgcn_mfma_f32_32x32x16_bf16(am, bm, acc, 0, 0, 0);
                acc = __builtin_amdgcn_mfma_f32_32x32x16_bf16(al, bh, acc, 0, 0, 0);
            }
#pragma unroll
            for (int i = 0; i < 16; i++) { accD[i] += (double)acc[i]; acc[i] = 0.f; }
        }
    }

    {
        int p = pgw * 32 + n;
        int py = p >> 4, pxx = p & 15;
        int gp = (y0 + py) * 64 + x0 + pxx;
        const int row_hi = 4 * g;
#pragma unroll
        for (int rg = 0; rg < 16; rg++) {
            int co = yb * 64 + cgw * 32 + (rg & 3) + 8 * (rg >> 2) + row_hi;
            pacc[(size_t)kh * 2097152 + (size_t)co * 4096 + gp] = (float)accD[rg];
        }
    }
}

// Fallback (ws too small for preW): runtime-split kernel, R9/R11 verbatim.
__global__ __launch_bounds__(512) void k_conv1m_fb(const float* __restrict__ fx, const float* __restrict__ w1,
                                                   float* __restrict__ pacc) {
    __shared__ u16 sA[3 * 9472];
    __shared__ u16 sB[3 * 3600];
    u32* const sA32 = (u32*)sA;
    const int tid = threadIdx.x;
    const int lane = tid & 63;
    const int wid = tid >> 6;
    const int cgw = wid >> 2;
    const int pgw = wid & 3;
    const int n = lane & 31;
    const int g = lane >> 5;
    const int bid = blockIdx.x;
    const int yb = bid & 7;
    const int rest = bid >> 3;
    const int bpx = rest & 31;
    const int kh = rest >> 5;
    const int y0 = (bpx >> 2) * 8, x0 = (bpx & 3) * 16;
    const int co0 = yb * 64;
    const int ci_base = kh * 512;

    int wgp[9], wlp[9];
#pragma unroll
    for (int j = 0; j < 9; j++) {
        int p = tid + j * 512;
        int co = p / 72, q = p - co * 72;
        int a = q & 7, b = q >> 3;
        wgp[j] = co * 9216 + (2 * a) * 9 + b;
        wlp[j] = co * 74 + b * 8 + a;
    }
    int fg0[6], fl[6];
#pragma unroll
    for (int j = 0; j < 6; j++) {
        int idx = tid + j * 512;
        bool wr = idx < 2880;
        int ci = idx / 180, rem = idx - ci * 180;
        int hy = rem / 18, hx = rem - hy * 18;
        int gy = y0 + hy - 1, gx = x0 + hx - 1;
        bool ok = wr && gy >= 0 && gy < 64 && gx >= 0 && gx < 64;
        fg0[j] = ok ? (ci * 4096 + gy * 64 + gx) : -1;
        fl[j] = wr ? (rem * 20 + ci) : -1;
    }

    f32x16 acc;
    double accD[16];
#pragma unroll
    for (int i = 0; i < 16; i++) { acc[i] = 0.f; accD[i] = 0.0; }

    float pw[18], pfA[6], pfB[6];
    {
        const float* wp = w1 + (size_t)co0 * 9216 + (size_t)ci_base * 9;
#pragma unroll
        for (int j = 0; j < 9; j++) { pw[2 * j] = wp[wgp[j]]; pw[2 * j + 1] = wp[wgp[j] + 9]; }
        const float* f0 = fx + (size_t)ci_base * 4096;
        const float* f1 = fx + (size_t)(ci_base + 16) * 4096;
#pragma unroll
        for (int j = 0; j < 6; j++) {
            pfA[j] = (fg0[j] >= 0) ? f0[fg0[j]] : 0.f;
            pfB[j] = (fg0[j] >= 0) ? f1[fg0[j]] : 0.f;
        }
    }

#pragma unroll 1
    for (int c = 0; c < 32; c++) {
        __syncthreads();
#pragma unroll
        for (int j = 0; j < 9; j++) {
            u16 h0, m0, l0, h1, m1, l1;
            split3(pw[2 * j], h0, m0, l0);
            split3(pw[2 * j + 1], h1, m1, l1);
            sA32[wlp[j]] = (u32)h0 | ((u32)h1 << 16);
            sA32[4736 + wlp[j]] = (u32)m0 | ((u32)m1 << 16);
            sA32[9472 + wlp[j]] = (u32)l0 | ((u32)l1 << 16);
        }
#pragma unroll
        for (int j = 0; j < 6; j++) {
            if (fl[j] >= 0) {
                u16 h, m, l;
                split3(pfA[j], h, m, l);
                sB[fl[j]] = h; sB[3600 + fl[j]] = m; sB[7200 + fl[j]] = l;
            }
        }
        __syncthreads();
        if (c < 31) {
            const float* wp = w1 + (size_t)co0 * 9216 + (size_t)(ci_base + (c + 1) * 16) * 9;
#pragma unroll
            for (int j = 0; j < 9; j++) { pw[2 * j] = wp[wgp[j]]; pw[2 * j + 1] = wp[wgp[j] + 9]; }
        }
#pragma unroll
        for (int j = 0; j < 6; j++) pfA[j] = pfB[j];
        if (c < 30) {
            const float* fp = fx + (size_t)(ci_base + (c + 2) * 16) * 4096;
#pragma unroll
            for (int j = 0; j < 6; j++) pfB[j] = (fg0[j] >= 0) ? fp[fg0[j]] : 0.f;
        }

#pragma unroll 1
        for (int dy = 0; dy < 3; dy++) {
#pragma unroll
            for (int dx = 0; dx < 3; dx++) {
                const int tap = dy * 3 + dx;
                const int aoff = (cgw * 32 + n) * 148 + tap * 16 + g * 8;
                bf16x8 ah = ldsfrag(&sA[aoff]);
                bf16x8 am = ldsfrag(&sA[9472 + aoff]);
                bf16x8 al = ldsfrag(&sA[18944 + aoff]);
                const int loc = (pgw * 2 + (n >> 4) + dy) * 18 + (n & 15) + dx;
                const int boff = loc * 20 + g * 8;
                bf16x8 bh = ldsfrag(&sB[boff]);
                bf16x8 bm = ldsfrag(&sB[3600 + boff]);
                bf16x8 bl = ldsfrag(&sB[7200 + boff]);
                acc = __builtin_amdgcn_mfma_f32_32x32x16_bf16(ah, bh, acc, 0, 0, 0);
                acc = __builtin_amdgcn_mfma_f32_32x32x16_bf16(ah, bm, acc, 0, 0, 0);
                acc = __builtin_amdgcn_mfma_f32_32x32x16_bf16(am, bh, acc, 0, 0, 0);
                acc = __builtin_amdgcn_mfma_f32_32x32x16_bf16(ah, bl, acc, 0, 0, 0);
                acc = __builtin_amdgcn_mfma_f32_32x32x16_bf16(am, bm, acc, 0, 0, 0);
                acc = __builtin_amdgcn_mfma_f32_32x32x16_bf16(al, bh, acc, 0, 0, 0);
            }
#pragma unroll
            for (int i = 0; i < 16; i++) { accD[i] += (double)acc[i]; acc[i] = 0.f; }
        }
    }

    {
        int p = pgw * 32 + n;
        int py = p >> 4, pxx = p & 15;
        int gp = (y0 + py) * 64 + x0 + pxx;
        const int row_hi = 4 * g;
#pragma unroll
        for (int rg = 0; rg < 16; rg++) {
            int co = co0 + cgw * 32 + (rg & 3) + 8 * (rg >> 2) + row_hi;
            pacc[(size_t)kh * 2097152 + (size_t)co * 4096 + gp] = (float)accD[rg];
        }
    }
}

// 1x1 convs, R11's 256-block shape, k_comb fused into x-staging (R13-validated).
__global__ __launch_bounds__(256) void k_conv23q(const float* __restrict__ pacc,
                                                 const float* __restrict__ b1,
                                                 const float* __restrict__ w2, const float* __restrict__ w3,
                                                 double* __restrict__ pox) {
    __shared__ float xs[32 * 64];     // [ci][px]
    __shared__ float wsh[60 * 128];   // [o][ci]
    const int tid = threadIdx.x;
    const int px0 = blockIdx.x * 64;
    const int cib = blockIdx.y * 128;
    const int px = tid & 63;
    const int og = tid >> 6;          // 0..3 -> o = og*15 + j

#pragma unroll
    for (int k = 0; k < 30; k++) {
        int e = tid + k * 256;
        int o = e >> 7, ci = e & 127;
        float wv = (o < 12) ? w2[o * 512 + cib + ci] : w3[(size_t)(o - 12) * 512 + cib + ci];
        wsh[o * 128 + ci] = wv;
    }

    double acc[15];
#pragma unroll
    for (int j = 0; j < 15; j++) acc[j] = 0.0;

#pragma unroll 1
    for (int ch = 0; ch < 4; ch++) {
        __syncthreads();
#pragma unroll
        for (int k = 0; k < 8; k++) {
            int e = tid + k * 256;
            int ci = e >> 6, p = e & 63;
            int cig = cib + ch * 32 + ci;
            size_t gi = (size_t)cig * 4096 + px0 + p;
            double v = (double)pacc[gi] + (double)pacc[2097152 + gi] + (double)b1[cig];
            xs[ci * 64 + p] = fmaxf((float)v, 0.f);   // bitwise = validated k_comb
        }
        __syncthreads();
#pragma unroll 1
        for (int ci = 0; ci < 32; ci++) {
            double xd = (double)xs[ci * 64 + px];
            const float* wrow = &wsh[ch * 32 + ci];
#pragma unroll
            for (int j = 0; j < 15; j++)
                acc[j] = fma(xd, (double)wrow[(og * 15 + j) * 128], acc[j]);
        }
    }
#pragma unroll
    for (int j = 0; j < 15; j++) {
        int o = og * 15 + j;
        pox[((size_t)o * 4 + blockIdx.y) * 4096 + px0 + px] = acc[j];
    }
}

// scores: combine ci-quarter partials (+b2, round f32), f64 sigmoid, histogram.
__global__ __launch_bounds__(256) void k_scores(const double* __restrict__ pox,
                                                const float* __restrict__ b2,
                                                float* __restrict__ scores, u32* __restrict__ hist) {
    int idx = blockIdx.x * 256 + threadIdx.x;
    if (idx >= A_TOTAL) return;
    int px = idx / 12, a = idx - px * 12;
    double t = 0.0;
#pragma unroll
    for (int q = 0; q < 4; q++) t += pox[((size_t)a * 4 + q) * 4096 + px];
    float o = (float)(t + (double)b2[a]);
    float s = (float)(1.0 / (1.0 + exp(-(double)o)));
    scores[idx] = s;
    atomicAdd(&hist[__float_as_uint(s) >> 16], 1u);
}

// find boundary bin B1 so that count(bins >= B1) >= 2000, count(bins > B1) < 2000
__global__ __launch_bounds__(256) void k_scanhist(const u32* __restrict__ hist, u32* __restrict__ misc) {
    __shared__ u32 csum[256];
    __shared__ u32 cb[256];
    __shared__ int s_cidx;
    __shared__ u32 s_cacc;
    int t = threadIdx.x;
    u32 sum = 0;
    const uint4* h4 = (const uint4*)(hist + t * 256);
    for (int j = 0; j < 64; j++) { uint4 v = h4[j]; sum += v.x + v.y + v.z + v.w; }
    csum[t] = sum;
    __syncthreads();
    if (t == 0) {
        u32 acc = 0;
        int c = 255;
        for (; c > 0; c--) {
            if (acc + csum[c] >= NKEEP) break;
            acc += csum[c];
        }
        s_cidx = c;
        s_cacc = acc;
    }
    __syncthreads();
    cb[t] = hist[s_cidx * 256 + t];
    __syncthreads();
    if (t == 0) {
        u32 acc = s_cacc;
        int b = 255;
        for (; b > 0; b--) {
            acc += cb[b];
            if (acc >= NKEEP) break;
        }
        misc[1] = (u32)(s_cidx * 256 + b);
    }
}

// compact + WIDE box decode: winner threads decode their candidate's box (f64 math,
// identical combine order/rounding to R13's sort-epilogue) into boxes4[slot].
__global__ __launch_bounds__(256) void k_compact(const float* __restrict__ scores, u32* __restrict__ misc,
                                                 const double* __restrict__ pox, const float* __restrict__ b3,
                                                 const int* __restrict__ imh, const int* __restrict__ imw,
                                                 u64* __restrict__ keys, float* __restrict__ boxes4) {
    int idx = blockIdx.x * 256 + threadIdx.x;
    if (idx >= A_TOTAL) return;
    u32 bits = __float_as_uint(scores[idx]);
    if ((bits >> 16) < misc[1]) return;
    u32 slot = atomicAdd(&misc[0], 1u);
    if (slot >= SORTN) return;
    keys[slot] = ((u64)bits << 32) | (u64)(~(u32)idx);

    int px = idx / 12, a = idx - px * 12;
    float d[4];
#pragma unroll
    for (int c = 0; c < 4; c++) {
        int oo = 12 + a * 4 + c;
        double u = 0.0;
#pragma unroll
        for (int q = 0; q < 4; q++) u += pox[((size_t)oo * 4 + q) * 4096 + px];
        d[c] = (float)(u + (double)b3[a * 4 + c]);
    }
    int py = px >> 6, pxx = px & 63;
    double cx = pxx * 16.0 + 8.0, cy = py * 16.0 + 8.0;
    int si = a / 3, ri = a - si * 3;
    double scale = (double)(32 << si);
    double ratio = 0.5 * (double)(1 << ri);
    double sq = sqrt(ratio);
    double aw = scale * sq, ah = scale / sq;
    double xc = cx + (double)d[0] * aw;
    double yc = cy + (double)d[1] * ah;
    double wv = aw * exp((double)d[2]);
    double hv = ah * exp((double)d[3]);
    float W = (float)imw[0], H = (float)imh[0];
    boxes4[slot * 4 + 0] = fminf(fmaxf((float)(xc - wv * 0.5), 0.f), W);
    boxes4[slot * 4 + 1] = fminf(fmaxf((float)(yc - hv * 0.5), 0.f), H);
    boxes4[slot * 4 + 2] = fminf(fmaxf((float)(xc + wv * 0.5), 0.f), W);
    boxes4[slot * 4 + 3] = fminf(fmaxf((float)(yc + hv * 0.5), 0.f), H);
}

// bitonic sort 4096 keys DESC; epilogue gathers pre-decoded boxes by slot + suppws.
__global__ __launch_bounds__(1024) void k_sort(const u64* __restrict__ keys, const u64* __restrict__ keys_ro,
                                               const float* __restrict__ boxes4,
                                               float* __restrict__ cand5, u64* __restrict__ suppws) {
    (void)keys_ro;
    __shared__ u64 lk[SORTN];
    __shared__ u16 slotof[SORTN];   // sorted position -> original slot
    int t = threadIdx.x;
#pragma unroll
    for (int r = 0; r < 4; r++) {
        int i = r * 1024 + t;
        lk[i] = (keys[i] & ~0xFFFFull) | (u64)(u16)i;   // low 16 bits = slot (idx low bits unused for order? keep full key)
    }
    // NOTE: we must preserve exact (score,idx) ordering; low 16 bits of ~idx matter.
    // So instead store slot in a parallel array and move it alongside during swaps.
#pragma unroll
    for (int r = 0; r < 4; r++) {
        int i = r * 1024 + t;
        lk[i] = keys[i];
        slotof[i] = (u16)i;
    }
    for (int kk = 2; kk <= SORTN; kk <<= 1) {
        for (int jj = kk >> 1; jj > 0; jj >>= 1) {
            __syncthreads();
#pragma unroll
            for (int rep = 0; rep < 4; rep++) {
                int i = rep * 1024 + t;
                int ixj = i ^ jj;
                if (ixj > i) {
                    u64 a = lk[i], b = lk[ixj];
                    bool sw = ((i & kk) == 0) ? (a < b) : (a > b);
                    if (sw) {
                        lk[i] = b; lk[ixj] = a;
                        u16 sa = slotof[i], sb = slotof[ixj];
                        slotof[i] = sb; slotof[ixj] = sa;
                    }
                }
            }
        }
    }
    __syncthreads();
#pragma unroll
    for (int rep = 0; rep < 2; rep++) {
        int i = rep * 1024 + t;
        bool suppb = true;
        float c0 = 0.f, c1 = 0.f, c2 = 0.f, c3 = 0.f, cs = 0.f;
        if (i < NKEEP) {
            u64 key = lk[i];
            cs = __uint_as_float((u32)(key >> 32));
            int slot = slotof[i];
            c0 = boxes4[slot * 4 + 0];
            c1 = boxes4[slot * 4 + 1];
            c2 = boxes4[slot * 4 + 2];
            c3 = boxes4[slot * 4 + 3];
            bool valid = ((c2 - c0) >= 16.f) && ((c3 - c1) >= 16.f) && (cs >= 0.05f);
            suppb = !valid;
        }
        cand5[i * 5 + 0] = c0;
        cand5[i * 5 + 1] = c1;
        cand5[i * 5 + 2] = c2;
        cand5[i * 5 + 3] = c3;
        cand5[i * 5 + 4] = cs;
        u64 bal = __ballot(suppb ? 1 : 0);
        if ((t & 63) == 0) suppws[i >> 6] = bal;
    }
}

// IoU > 0.7 bitmask, 64x64 tiles
__global__ __launch_bounds__(64) void k_mask(const float* __restrict__ cand5, u64* __restrict__ mask) {
    __shared__ float cb[64][5];
    int t = threadIdx.x;
    int bi = blockIdx.y, bj = blockIdx.x;
    int j = bj * 64 + t;
    {
        float b0 = cand5[j * 5 + 0], b1v = cand5[j * 5 + 1], b2v = cand5[j * 5 + 2], b3v = cand5[j * 5 + 3];
        cb[t][0] = b0; cb[t][1] = b1v; cb[t][2] = b2v; cb[t][3] = b3v;
        cb[t][4] = (b2v - b0) * (b3v - b1v);
    }
    __syncthreads();
    int i = bi * 64 + t;
    float r0 = cand5[i * 5 + 0], r1 = cand5[i * 5 + 1], r2 = cand5[i * 5 + 2], r3 = cand5[i * 5 + 3];
    float ra = (r2 - r0) * (r3 - r1);
    u64 bits = 0ull;
#pragma unroll 4
    for (int c = 0; c < 64; c++) {
        float lx = fmaxf(r0, cb[c][0]);
        float ly = fmaxf(r1, cb[c][1]);
        float rx = fminf(r2, cb[c][2]);
        float ry = fminf(r3, cb[c][3]);
        float w = fmaxf(rx - lx, 0.f);
        float h = fmaxf(ry - ly, 0.f);
        float inter = w * h;
        float iou = inter / fmaxf(ra + cb[c][4] - inter, 1e-6f);
        if (iou > 0.7f) bits |= (1ull << c);
    }
    mask[(size_t)i * 32 + bj] = bits;
}

// single-wave greedy NMS scan with depth-8 prefetch; writes first <=300 kept rows
__global__ __launch_bounds__(64) void k_scan(const u64* __restrict__ mask, const float* __restrict__ cand5,
                                             const u64* __restrict__ suppws, float* __restrict__ out) {
    int lane = threadIdx.x;
    u64 supp = (lane < 32) ? suppws[lane] : 0ull;
    u64 bufA[8], bufB[8];
    float dA[8], dB[8];
#pragma unroll
    for (int k = 0; k < 8; k++) {
        bufA[k] = (lane < 32) ? mask[(size_t)k * 32 + lane] : 0ull;
        dA[k] = (lane < 5) ? cand5[k * 5 + lane] : 0.f;
    }
    int kcount = 0;
    for (int gq = 0; gq < 256; gq++) {
        int base = gq * 8;
        if (gq < 255) {
            int nb = base + 8;
#pragma unroll
            for (int k = 0; k < 8; k++) {
                bufB[k] = (lane < 32) ? mask[(size_t)(nb + k) * 32 + lane] : 0ull;
                dB[k] = (lane < 5) ? cand5[(nb + k) * 5 + lane] : 0.f;
            }
        }
        int w = gq >> 3;
        u64 cur = __shfl(supp, w);
#pragma unroll
        for (int k = 0; k < 8; k++) {
            int i = base + k;
            if (i < NKEEP && !((cur >> (i & 63)) & 1ull)) {
                if (kcount < NTOPK) {
                    if (lane < 5) out[kcount * 5 + lane] = dA[k];
                    kcount++;
                }
                supp |= bufA[k];
                cur |= __shfl(bufA[k], w);
            }
        }
        if (kcount >= NTOPK) return;
#pragma unroll
        for (int k = 0; k < 8; k++) { bufA[k] = bufB[k]; dA[k] = dB[k]; }
    }
}

extern "C" void kernel_launch(void* const* d_in, const int* in_sizes, int n_in,
                              void* d_out, int out_size, void* d_ws, size_t ws_size,
                              hipStream_t stream) {
    (void)in_sizes; (void)n_in; (void)out_size;
    const float* fx = (const float*)d_in[0];
    const float* w1 = (const float*)d_in[1];
    const float* b1 = (const float*)d_in[2];
    const float* w2 = (const float*)d_in[3];
    const float* b2 = (const float*)d_in[4];
    const float* w3 = (const float*)d_in[5];
    const float* b3 = (const float*)d_in[6];
    const int* imh = (const int*)d_in[7];
    const int* imw = (const int*)d_in[8];

    char* ws = (char*)d_ws;
    float*  pacc   = (float*)(ws + OFF_PACC);
    float*  scores = (float*)(ws + OFF_SCORES);
    u32*    hist   = (u32*)(ws + OFF_HIST);
    u64*    keys   = (u64*)(ws + OFF_KEYS);
    float*  cand5  = (float*)(ws + OFF_CAND5);
    u64*    mask   = (u64*)(ws + OFF_MASK);
    float*  boxes4 = (float*)(ws + OFF_BOX4);
    u32*    misc   = (u32*)(ws + OFF_MISC);
    u64*    suppws = (u64*)(ws + OFF_MISC + 64);
    uint4*  preW   = (uint4*)(ws + OFF_PREW);
    double* pox    = (double*)(ws + OFF_POX);    // overlays preW (dead after conv1m)
    float*  out    = (float*)d_out;

    k_init<<<256, 256, 0, stream>>>(hist, keys, misc, out);
    if (ws_size >= WS_NEED) {
        k_splitw<<<dim3(32, 8, 2), 256, 0, stream>>>(w1, preW);
        k_conv1m<<<512, 512, 0, stream>>>(fx, preW, pacc);
    } else {
        k_conv1m_fb<<<512, 512, 0, stream>>>(fx, w1, pacc);
    }
    k_conv23q<<<dim3(64, 4), 256, 0, stream>>>(pacc, b1, w2, w3, pox);
    k_scores<<<192, 256, 0, stream>>>(pox, b2, scores, hist);
    k_scanhist<<<1, 256, 0, stream>>>(hist, misc);
    k_compact<<<192, 256, 0, stream>>>(scores, misc, pox, b3, imh, imw, keys, boxes4);
    k_sort<<<1, 1024, 0, stream>>>(keys, keys, boxes4, cand5, suppws);
    k_mask<<<dim3(32, 32), 64, 0, stream>>>(cand5, mask);
    k_scan<<<1, 64, 0, stream>>>(mask, cand5, suppws, out);
}